// Round 3
// baseline (669.219 us; speedup 1.0000x reference)
//
#include <hip/hip_runtime.h>

// cumprod along dim=1 of (B=32, L=4096, C=512) fp32.
// Round-3 changes (vs round 2):
//  1. W 64->128, block 512->1024 threads: total waves 4096->8192 ->
//     32 waves/CU (round-2 counter showed occupancy stuck at 16 waves/CU
//     because the grid itself was the cap, not launch_bounds).
//  2. PLAIN stores (nt removed): round-2 WRITE_SIZE showed 2.07x the
//     output size. Theory: harness re-poisons `out` each iter -> dirty
//     lines in L2/L3; nt (no-allocate) stores write through AND the
//     stale dirty poison lines also write back -> ~2x. Plain stores
//     write-allocate and merge -> 1x. nt kept on loads only.
//
// Structure per 512-l chunk: 4 float4/thread in regs -> local chain ->
// in-wave shuffle scan over 8 w-slots (no barrier) -> 16 wave-totals
// through LDS with ONE raw s_barrier (lgkmcnt only, no vmcnt drain) ->
// apply carry -> store. Next chunk's loads issued before the scan,
// in flight across the barrier.
// Ideal traffic = 268 MB read + 268 MB write -> ~83 us @6.45 TB/s.

typedef float f4 __attribute__((ext_vector_type(4)));

constexpr int L  = 4096;  // scan length
constexpr int C  = 512;   // channels
constexpr int C4 = C / 4; // float4 groups per row = 128
constexpr int CG = 8;     // float4 groups per block (32 channels)
constexpr int W  = 128;   // l-segments per chunk (threads along l) [was 64]
constexpr int KE = 4;     // l elements per thread per chunk
constexpr int CL = W * KE;         // 512 l per chunk
constexpr int NCHUNK = L / CL;     // 8
constexpr int NWAVE = CG * W / 64; // 16 waves per block
constexpr int WPW = 64 / CG;       // w-slots per wave = 8

__device__ __forceinline__ f4 shflup(f4 v, int lanes) {
    f4 r;
#pragma unroll
    for (int j = 0; j < 4; ++j) r[j] = __shfl_up(v[j], lanes, 64);
    return r;
}

__global__ __launch_bounds__(CG * W, 8)  // 1024 thr; VGPR<=64 -> 2 blocks/CU = 32 waves/CU
void cumprod_kernel(const f4* __restrict__ x, f4* __restrict__ out) {
    // double-buffered wave totals: no trailing barrier needed
    __shared__ f4 s[2][NWAVE][CG + 1];

    const int tid  = threadIdx.x;
    const int c4   = tid & (CG - 1);   // fast index: channel -> coalescing
    const int w    = tid >> 3;         // l-segment within chunk, 0..127
    const int lane = tid & 63;
    const int wi   = lane >> 3;        // w-slot within wave, 0..7
    const int ww   = tid >> 6;         // wave id, 0..15
    const int c4g  = blockIdx.x * CG + c4;
    const int b    = blockIdx.y;
    const int base = (b * L) * C4 + c4g;  // fits int32 (max ~16.8M)

    f4 carry = {1.f, 1.f, 1.f, 1.f};

    // ---- prefetch chunk 0 ----
    f4 p[KE];
    {
        const int lb = base + (w * KE) * C4;
#pragma unroll
        for (int i = 0; i < KE; ++i)
            p[i] = __builtin_nontemporal_load(&x[lb + i * C4]);
    }

    for (int chunk = 0; chunk < NCHUNK; ++chunk) {
        // consume prefetch
        f4 v[KE];
#pragma unroll
        for (int i = 0; i < KE; ++i) v[i] = p[i];

        // issue next chunk's loads NOW -> in flight across scan+store+barrier
        if (chunk + 1 < NCHUNK) {
            const int lb = base + ((chunk + 1) * CL + w * KE) * C4;
#pragma unroll
            for (int i = 0; i < KE; ++i)
                p[i] = __builtin_nontemporal_load(&x[lb + i * C4]);
        }

        // ---- local inclusive products (register chain) ----
#pragma unroll
        for (int i = 1; i < KE; ++i) v[i] = v[i] * v[i - 1];

        // ---- in-wave inclusive scan of segment products over 8 w-slots ----
        f4 seg = v[KE - 1];
#pragma unroll
        for (int d = 1; d < WPW; d <<= 1) {
            f4 t = shflup(seg, d * CG);   // value from w-slot (wi - d)
            if (wi >= d) seg = seg * t;
        }

        // exclusive-within-wave prefix (segments ww*8 .. ww*8+wi-1)
        f4 exw = shflup(seg, CG);

        // wave totals -> LDS (lanes with wi==7 hold them)
        if (wi == WPW - 1) s[chunk & 1][ww][c4] = seg;

        // barrier WITHOUT vmcnt drain: LDS-visibility only
        asm volatile("s_waitcnt lgkmcnt(0)" ::: "memory");
        __builtin_amdgcn_s_barrier();

        // prefix over lower waves' totals + chunk total (loop bound uniform per wave)
        f4 wpre = {1.f, 1.f, 1.f, 1.f};
        f4 tot  = {1.f, 1.f, 1.f, 1.f};
#pragma unroll
        for (int j = 0; j < NWAVE; ++j) {
            f4 sj = s[chunk & 1][j][c4];
            if (j < ww) wpre = wpre * sj;
            tot = tot * sj;
        }

        f4 pref = carry * wpre;
        if (wi > 0) pref = pref * exw;

        // ---- apply prefix and store (plain store: merge with dirty
        //      poison lines in L2/L3, single writeback) ----
        const int lb = base + (chunk * CL + w * KE) * C4;
#pragma unroll
        for (int i = 0; i < KE; ++i)
            out[lb + i * C4] = pref * v[i];

        carry = carry * tot;
        // no trailing barrier: next chunk writes the other s[] buffer
    }
}

extern "C" void kernel_launch(void* const* d_in, const int* in_sizes, int n_in,
                              void* d_out, int out_size, void* d_ws, size_t ws_size,
                              hipStream_t stream) {
    const f4* x = (const f4*)d_in[0];
    f4* out = (f4*)d_out;

    const int B = in_sizes[0] / (L * C);  // = 32

    dim3 grid(C4 / CG, B);   // (16, 32) = 512 blocks x 16 waves = 32 waves/CU
    dim3 block(CG * W);      // 1024 threads
    cumprod_kernel<<<grid, block, 0, stream>>>(x, out);
}

// Round 6
// 434.289 us; speedup vs baseline: 1.5410x; 1.5410x over previous
//
#include <hip/hip_runtime.h>

// cumprod along dim=1 of (B=32, L=4096, C=512) fp32.
// Round-6 = final resubmit of the CG=16 experiment (r4/r5 died to container
// infra at acquire/run level; kernel audited: uniform barriers, in-bounds,
// no spill -> no mechanism to kill a container).
// Change under test: CG 8 -> 16 (block owns 16 float4-channels = 256 B/row).
// Evidence: WRITE amplification tracks access granularity, not store flavor:
//   CG=8 segments are 128 B -> nt stores 2.07x WRITE (r2), plain 3.7x+RFO (r3);
//   contiguous fills show exactly 1.0x. Theory: 256-B L2<->fabric granule.
// Geometry: 1024 thr/block (16 waves), grid (8, 32) = 256 blocks = 1/CU,
// 16 waves/CU (round-1 residency). KE=8 (MLP), nt loads+stores.
// Scan per 512-l chunk: 8-deep register chain -> in-wave scan over 4 w-slots
// (2 shuffles) -> 16 wave totals via LDS, wi-split read (4 reads/thread) +
// butterfly product across wi -> ONE raw s_barrier (lgkmcnt only, no vmcnt
// drain) -> apply carry -> 256-B-contiguous nt store. Next chunk's loads are
// issued before the scan and stay in flight across the barrier.
// Ideal traffic 268+268 MB -> ~83 us @6.4 TB/s.

typedef float f4 __attribute__((ext_vector_type(4)));

constexpr int L  = 4096;   // scan length
constexpr int C  = 512;    // channels
constexpr int C4 = C / 4;  // float4 groups per row = 128
constexpr int CG = 16;     // float4 groups per block strip = 256 B
constexpr int W  = 64;     // l-segments per chunk
constexpr int KE = 8;      // l elements per thread per chunk
constexpr int CL = W * KE;         // 512 l per chunk
constexpr int NCHUNK = L / CL;     // 8
constexpr int NWAVE = CG * W / 64; // 16 waves per block
constexpr int WPW = 64 / CG;       // w-slots per wave = 4

__device__ __forceinline__ f4 shflup(f4 v, int lanes) {
    f4 r;
#pragma unroll
    for (int j = 0; j < 4; ++j) r[j] = __shfl_up(v[j], lanes, 64);
    return r;
}
__device__ __forceinline__ f4 shflxor(f4 v, int mask) {
    f4 r;
#pragma unroll
    for (int j = 0; j < 4; ++j) r[j] = __shfl_xor(v[j], mask, 64);
    return r;
}

__global__ __launch_bounds__(CG * W, 4)  // 1024 thr; VGPR<=128 -> 16 waves/CU
void cumprod_kernel(const f4* __restrict__ x, f4* __restrict__ out) {
    // double-buffered wave totals: no trailing barrier needed
    __shared__ f4 s[2][NWAVE][CG + 1];

    const int tid  = threadIdx.x;
    const int c4   = tid & (CG - 1);   // channel within strip, 0..15
    const int w    = tid >> 4;         // l-segment within chunk, 0..63
    const int lane = tid & 63;
    const int wi   = lane >> 4;        // w-slot within wave, 0..3 (w = ww*4+wi)
    const int ww   = tid >> 6;         // wave id, 0..15
    const int c4g  = blockIdx.x * CG + c4;
    const int b    = blockIdx.y;
    const int base = (b * L) * C4 + c4g;  // fits int32 (max 2^24-1)

    f4 carry = {1.f, 1.f, 1.f, 1.f};

    // ---- prefetch chunk 0 ----
    f4 p[KE];
    {
        const int lb = base + (w * KE) * C4;
#pragma unroll
        for (int i = 0; i < KE; ++i)
            p[i] = __builtin_nontemporal_load(&x[lb + i * C4]);
    }

    for (int chunk = 0; chunk < NCHUNK; ++chunk) {
        f4 v[KE];
#pragma unroll
        for (int i = 0; i < KE; ++i) v[i] = p[i];

        // issue next chunk's loads NOW -> in flight across scan+store+barrier
        if (chunk + 1 < NCHUNK) {
            const int lb = base + ((chunk + 1) * CL + w * KE) * C4;
#pragma unroll
            for (int i = 0; i < KE; ++i)
                p[i] = __builtin_nontemporal_load(&x[lb + i * C4]);
        }

        // ---- local inclusive products (register chain) ----
#pragma unroll
        for (int i = 1; i < KE; ++i) v[i] = v[i] * v[i - 1];

        // ---- in-wave inclusive scan over 4 w-slots (lanes share c4) ----
        f4 seg = v[KE - 1];
        {
            f4 t = shflup(seg, CG);        // slot wi-1
            if (wi >= 1) seg = seg * t;
            t = shflup(seg, 2 * CG);       // slot wi-2
            if (wi >= 2) seg = seg * t;
        }
        // exclusive-within-wave prefix (slots < wi); valid for wi>0
        f4 exw = shflup(seg, CG);

        // wave totals -> LDS (wi==3 lanes hold inclusive wave total)
        if (wi == WPW - 1) s[chunk & 1][ww][c4] = seg;

        // barrier WITHOUT vmcnt drain: LDS-visibility only
        asm volatile("s_waitcnt lgkmcnt(0)" ::: "memory");
        __builtin_amdgcn_s_barrier();

        // ---- cross-wave combine, wi-split: each lane reads 4 of the 16
        //      wave totals (j = wi*4+r), then butterfly-product across wi ----
        f4 pall = {1.f, 1.f, 1.f, 1.f};  // -> chunk total
        f4 plt  = {1.f, 1.f, 1.f, 1.f};  // -> product of wave totals j < ww
#pragma unroll
        for (int r = 0; r < 4; ++r) {
            const int j = wi * 4 + r;
            f4 sj = s[chunk & 1][j][c4];
            pall = pall * sj;
            if (j < ww) plt = plt * sj;
        }
        {
            f4 q = shflxor(pall, CG);     pall = pall * q;
            q = shflxor(pall, 2 * CG);    pall = pall * q;
            q = shflxor(plt, CG);         plt = plt * q;
            q = shflxor(plt, 2 * CG);     plt = plt * q;
        }

        f4 pref = carry * plt;
        if (wi > 0) pref = pref * exw;

        // ---- apply prefix and store (256-B contiguous nt store) ----
        const int lb = base + (chunk * CL + w * KE) * C4;
#pragma unroll
        for (int i = 0; i < KE; ++i)
            __builtin_nontemporal_store(pref * v[i], &out[lb + i * C4]);

        carry = carry * pall;
        // no trailing barrier: next chunk writes the other s[] buffer
    }
}

extern "C" void kernel_launch(void* const* d_in, const int* in_sizes, int n_in,
                              void* d_out, int out_size, void* d_ws, size_t ws_size,
                              hipStream_t stream) {
    const f4* x = (const f4*)d_in[0];
    f4* out = (f4*)d_out;

    const int B = in_sizes[0] / (L * C);  // = 32

    dim3 grid(C4 / CG, B);   // (8, 32) = 256 blocks = 1/CU, 16 waves/CU
    dim3 block(CG * W);      // 1024 threads = 16 waves
    cumprod_kernel<<<grid, block, 0, stream>>>(x, out);
}